// Round 12
// baseline (501.893 us; speedup 1.0000x reference)
//
#include <hip/hip_runtime.h>
#include <hip/hip_bf16.h>
#include <stdint.h>

typedef __bf16 bf16;
typedef __bf16 bf16x4 __attribute__((ext_vector_type(4)));
typedef __bf16 bf16x8 __attribute__((ext_vector_type(8)));
typedef float f32x4 __attribute__((ext_vector_type(4)));

#define MFMA(a, b, c) __builtin_amdgcn_mfma_f32_16x16x32_bf16(a, b, c, 0, 0, 0)
#define GL(p) ((const __attribute__((address_space(1))) void*)(p))
#define SH(p) ((__attribute__((address_space(3))) void*)(p))

// ---- prep: W transposes (bf16), bias concat, zero d_out + group flags ----
__device__ inline void tp(const float* W, bf16* WT, int id, int shiftK, int N) {
  int K = 1 << shiftK;
  int n = id >> shiftK;
  int k = id & (K - 1);
  WT[id] = (bf16)W[(size_t)k * N + n];
}

__global__ __launch_bounds__(256) void prep_all(
    const float* __restrict__ W1, const float* __restrict__ W2,
    bf16* __restrict__ W1T, bf16* __restrict__ W2T,
    const float* __restrict__ Wpre, const float* __restrict__ Wloc,
    const float* __restrict__ Wgcn, const float* __restrict__ Wpost,
    bf16* __restrict__ WpreLocT, bf16* __restrict__ Wg0T, bf16* __restrict__ Wg1T,
    bf16* __restrict__ WpostT,
    const float* __restrict__ bpre, const float* __restrict__ bloc,
    float* __restrict__ biasPL, float* __restrict__ outq, int* __restrict__ flags) {
  __shared__ bf16 tile[64 * 68];
  int blk = blockIdx.x;
  int tid = threadIdx.x;
  if (blk < 128) {                       // tiled transpose W1/W2 (512x512 each)
    const float* W = (blk < 64) ? W1 : W2;
    bf16* WT = (blk < 64) ? W1T : W2T;
    int t = blk & 63;
    int tk0 = (t >> 3) * 64, tn0 = (t & 7) * 64;
#pragma unroll
    for (int p = 0; p < 4; p++) {
      int kr = p * 16 + (tid >> 4), nc = (tid & 15) * 4;
      float4 f = *(const float4*)(W + (size_t)(tk0 + kr) * 512 + tn0 + nc);
      bf16x4 v; v[0] = (bf16)f.x; v[1] = (bf16)f.y; v[2] = (bf16)f.z; v[3] = (bf16)f.w;
      *(bf16x4*)&tile[kr * 68 + nc] = v;
    }
    __syncthreads();
#pragma unroll
    for (int p = 0; p < 4; p++) {
      int nr = p * 16 + (tid >> 4), kc = (tid & 15) * 4;
      bf16x4 v;
#pragma unroll
      for (int i = 0; i < 4; i++) v[i] = tile[(kc + i) * 68 + nr];
      *(bf16x4*)(WT + (size_t)(tn0 + nr) * 512 + tk0 + kc) = v;
    }
    return;
  }
  blk -= 128;
  if (blk < 448) {                       // small transposes
    int id = blk * 256 + tid;
    if (id < 16384) { tp(Wpre, WpreLocT, id, 7, 128); return; } id -= 16384;
    if (id < 32768) { tp(Wloc, WpreLocT + 16384, id, 7, 256); return; } id -= 32768;
    if (id < 16384) { tp(Wgcn, Wg0T, id, 7, 128); return; } id -= 16384;
    if (id < 16384) { tp(Wgcn + 16384, Wg1T, id, 7, 128); return; } id -= 16384;
    tp(Wpost, WpostT, id, 7, 256);
    return;
  }
  blk -= 448;
  if (blk == 0) {                        // bias concat + flag zero (512 ints)
    if (tid < 128) biasPL[tid] = bpre[tid];
    biasPL[128 + tid] = bloc[tid];
    flags[tid] = 0;
    flags[256 + tid] = 0;
    return;
  }
  blk -= 1;
  // zero d_out: 64 blocks x 256 threads x 4 float4 = 262144 floats
  float4 z = {0.f, 0.f, 0.f, 0.f};
#pragma unroll
  for (int i = 0; i < 4; i++)
    ((float4*)outq)[(size_t)blk * 1024 + i * 256 + tid] = z;
}

// ---- per-m-tile 4-block barrier (siblings co-resident & same XCD) ----
__device__ inline void gbar(int* flag) {
  __syncthreads();                      // local stores issued & waited
  if (threadIdx.x == 0) {
    __threadfence();                    // release: publish to L2
    atomicAdd(flag, 1);
    while (__hip_atomic_load(flag, __ATOMIC_RELAXED, __HIP_MEMORY_SCOPE_AGENT) < 4)
      __builtin_amdgcn_s_sleep(8);
  }
  __syncthreads();
  __threadfence();                      // acquire: invalidate L1 before sibling reads
}

// ---- fused network kernel: phase A (k1c) -> B (K3) -> C (K4+qhead) ----
// 1024 blocks = 256 m-tile groups x 4 siblings, XCD-swizzled (group on one XCD).
// Grid == exact co-residency capacity at (256,4): flag barriers are safe.
__global__ __launch_bounds__(256, 4) void fused(
    const float* __restrict__ obs, const bf16* __restrict__ WpreLocT,
    const float* __restrict__ biasPL,
    const bf16* __restrict__ Wg0T, const bf16* __restrict__ Wg1T,
    const bf16* __restrict__ WpostT, const float* __restrict__ b_gcn,
    const float* __restrict__ b_post,
    const bf16* __restrict__ W1T, const float* __restrict__ b1,
    const bf16* __restrict__ W2T, const float* __restrict__ b2,
    const float* __restrict__ W3, const float* __restrict__ b3,
    bf16* __restrict__ loc, float* __restrict__ h, bf16* __restrict__ z1,
    float* __restrict__ outq, int* __restrict__ flags) {
  __shared__ bf16 smem[16384];
  bf16* As = smem;
  bf16* Bs = smem + 8192;

  const int tid = threadIdx.x;
  const int id = blockIdx.x;
  const int s = id >> 3;
  const int n_idx = s & 3;
  const int mt = (id & 7) + 8 * (s >> 2);
  const int m0 = mt * 128;
  const int n0 = n_idx * 128;

  const int lane = tid & 63, wave = tid >> 6;
  const int wm = (wave >> 1) * 64, wn = (wave & 1) * 64;
  const int lm = lane & 15, quad = lane >> 4;

  // ================= Phase A: pre/loc GEMM (+pool+chain+h on n_idx 0) ======
  if (n_idx < 3) {
    f32x4 acc[4][4] = {};
    for (int k0 = 0; k0 < 128; k0 += 64) {
#pragma unroll
      for (int it = 0; it < 4; it++) {
        int idx = it * 256 + tid;
        int row = idx >> 3;
        int c = idx & 7;
        int cv8 = c ^ (row & 7);
        int kk = k0 + cv8 * 8;
        const float* src = obs + (size_t)(m0 + row) * 128 + kk;
        float4 f0 = *(const float4*)src;
        float4 f1 = *(const float4*)(src + 4);
        bf16x8 v;
        v[0] = (bf16)f0.x; v[1] = (bf16)f0.y; v[2] = (bf16)f0.z; v[3] = (bf16)f0.w;
        v[4] = (bf16)f1.x; v[5] = (bf16)f1.y; v[6] = (bf16)f1.z; v[7] = (bf16)f1.w;
        *(bf16x8*)&As[row * 64 + c * 8] = v;
        const bf16* gb = WpreLocT + (size_t)(n0 + row) * 128 + kk;
        __builtin_amdgcn_global_load_lds(GL(gb), SH(&Bs[(idx & ~63) * 8]), 16, 0, 0);
      }
      __syncthreads();
#pragma unroll
      for (int ks = 0; ks < 2; ks++) {
        const int ua = quad + ks * 4;
        bf16x8 a[4], b[4];
#pragma unroll
        for (int i = 0; i < 4; i++) {
          int r = wm + lm + i * 16;
          a[i] = *(const bf16x8*)&As[r * 64 + ((ua ^ (r & 7)) * 8)];
        }
#pragma unroll
        for (int j = 0; j < 4; j++) {
          int r = wn + lm + j * 16;
          b[j] = *(const bf16x8*)&Bs[r * 64 + ((ua ^ (r & 7)) * 8)];
        }
#pragma unroll
        for (int i = 0; i < 4; i++)
#pragma unroll
          for (int j = 0; j < 4; j++)
            acc[i][j] = MFMA(a[i], b[j], acc[i][j]);
      }
      __syncthreads();
    }

    if (n_idx == 0) {
      bf16* xs = smem;                  // 16 x 136
      bf16* x2 = smem + 2176;           // 16 x 136
      bf16* gS = smem + 4352;           // 16 x 264
#pragma unroll
      for (int i = 0; i < 4; i++) {
        int sl = (wave >> 1) * 4 + i;
#pragma unroll
        for (int j = 0; j < 4; j++) {
          int col = wn + j * 16 + lm;
          float bb = biasPL[col];
          float v = 0.f;
#pragma unroll
          for (int r = 0; r < 4; r++) v += fmaxf(acc[i][j][r] + bb, 0.f);
          v += __shfl_xor(v, 16);
          v += __shfl_xor(v, 32);
          if (quad == 0) xs[sl * 136 + col] = (bf16)(v * 0.0625f);
          else if (quad == 1) xs[(8 + sl) * 136 + col] = (bf16)0.f;
        }
      }
      __syncthreads();
      {  // l0
        f32x4 c2[2] = {};
#pragma unroll
        for (int ku = 0; ku < 4; ++ku) {
          bf16x8 a = *(const bf16x8*)&xs[lm * 136 + (ku * 4 + quad) * 8];
#pragma unroll
          for (int jn = 0; jn < 2; ++jn) {
            int col = (wave * 2 + jn) * 16 + lm;
            bf16x8 b = *(const bf16x8*)&Wg0T[(size_t)col * 128 + ku * 32 + quad * 8];
            c2[jn] = MFMA(a, b, c2[jn]);
          }
        }
        __syncthreads();
#pragma unroll
        for (int jn = 0; jn < 2; ++jn) {
          int col = (wave * 2 + jn) * 16 + lm;
          float bb = b_gcn[col];
#pragma unroll
          for (int r = 0; r < 4; ++r)
            x2[(quad * 4 + r) * 136 + col] = (bf16)fmaxf(c2[jn][r] + bb, 0.f);
        }
      }
      __syncthreads();
      {  // l1
        f32x4 c2[2] = {};
#pragma unroll
        for (int ku = 0; ku < 4; ++ku) {
          bf16x8 a = *(const bf16x8*)&x2[lm * 136 + (ku * 4 + quad) * 8];
#pragma unroll
          for (int jn = 0; jn < 2; ++jn) {
            int col = (wave * 2 + jn) * 16 + lm;
            bf16x8 b = *(const bf16x8*)&Wg1T[(size_t)col * 128 + ku * 32 + quad * 8];
            c2[jn] = MFMA(a, b, c2[jn]);
          }
        }
        __syncthreads();
#pragma unroll
        for (int jn = 0; jn < 2; ++jn) {
          int col = (wave * 2 + jn) * 16 + lm;
          float bb = b_gcn[128 + col];
#pragma unroll
          for (int r = 0; r < 4; ++r)
            xs[(quad * 4 + r) * 136 + col] = (bf16)fmaxf(c2[jn][r] + bb, 0.f);
        }
      }
      __syncthreads();
      {  // l2 -> gS
        f32x4 c3[4] = {};
#pragma unroll
        for (int ku = 0; ku < 4; ++ku) {
          bf16x8 a = *(const bf16x8*)&xs[lm * 136 + (ku * 4 + quad) * 8];
#pragma unroll
          for (int jn = 0; jn < 4; ++jn) {
            int col = (wave * 4 + jn) * 16 + lm;
            bf16x8 b = *(const bf16x8*)&WpostT[(size_t)col * 128 + ku * 32 + quad * 8];
            c3[jn] = MFMA(a, b, c3[jn]);
          }
        }
#pragma unroll
        for (int jn = 0; jn < 4; ++jn) {
          int col = (wave * 4 + jn) * 16 + lm;
          float bb = b_post[col];
#pragma unroll
          for (int r = 0; r < 4; ++r)
            gS[(quad * 4 + r) * 264 + col] = (bf16)fmaxf(c3[jn][r] + bb, 0.f);
        }
      }
      __syncthreads();
      {  // h = g @ W1a + b1 (fp32)
        f32x4 hacc[8] = {};
#pragma unroll
        for (int ku = 0; ku < 8; ++ku) {
          bf16x8 a = *(const bf16x8*)&gS[lm * 264 + ku * 32 + quad * 8];
#pragma unroll
          for (int jn = 0; jn < 8; ++jn) {
            int col = (wave * 8 + jn) * 16 + lm;
            bf16x8 b = *(const bf16x8*)&W1T[(size_t)col * 512 + ku * 32 + quad * 8];
            hacc[jn] = MFMA(a, b, hacc[jn]);
          }
        }
        int sample0 = m0 >> 4;
#pragma unroll
        for (int jn = 0; jn < 8; ++jn) {
          int col = (wave * 8 + jn) * 16 + lm;
          float bb = b1[col];
#pragma unroll
          for (int r = 0; r < 4; ++r) {
            int row = quad * 4 + r;
            if (row < 8)
              h[(size_t)(sample0 + row) * 512 + col] = hacc[jn][r] + bb;
          }
        }
      }
    } else {
      // loc: coalesced store via LDS tile
#pragma unroll
      for (int i = 0; i < 4; i++)
#pragma unroll
        for (int j = 0; j < 4; j++) {
          int col = wn + j * 16 + lm;
          float bb = biasPL[n0 + col];
#pragma unroll
          for (int r = 0; r < 4; r++) {
            int row = wm + i * 16 + quad * 4 + r;
            smem[row * 128 + col] = (bf16)fmaxf(acc[i][j][r] + bb, 0.f);
          }
        }
      __syncthreads();
      const int coff = n0 - 128;
#pragma unroll
      for (int c = 0; c < 8; c++) {
        int ci = c * 256 + tid;
        int row = ci >> 4, col8 = (ci & 15) * 8;
        *(bf16x8*)&loc[(size_t)(m0 + row) * 256 + coff + col8] = *(const bf16x8*)&smem[row * 128 + col8];
      }
    }
  }
  gbar(&flags[mt]);

  // ================= Phase B: z1 = relu(loc @ W1b + h_rep), K=256 ==========
  {
    f32x4 acc[4][4] = {};
    for (int k0 = 0; k0 < 256; k0 += 64) {
#pragma unroll
      for (int it = 0; it < 4; it++) {
        int idx = it * 256 + tid;
        int row = idx >> 3;
        int c = idx & 7;
        int cv8 = c ^ (row & 7);
        int kk = k0 + cv8 * 8;
        const bf16* ga = loc + (size_t)(m0 + row) * 256 + kk;
        __builtin_amdgcn_global_load_lds(GL(ga), SH(&As[(idx & ~63) * 8]), 16, 0, 0);
        const bf16* gb = W1T + (size_t)(n0 + row) * 512 + 256 + kk;
        __builtin_amdgcn_global_load_lds(GL(gb), SH(&Bs[(idx & ~63) * 8]), 16, 0, 0);
      }
      __syncthreads();
#pragma unroll
      for (int ks = 0; ks < 2; ks++) {
        const int ua = quad + ks * 4;
        bf16x8 a[4], b[4];
#pragma unroll
        for (int i = 0; i < 4; i++) {
          int r = wm + lm + i * 16;
          a[i] = *(const bf16x8*)&As[r * 64 + ((ua ^ (r & 7)) * 8)];
        }
#pragma unroll
        for (int j = 0; j < 4; j++) {
          int r = wn + lm + j * 16;
          b[j] = *(const bf16x8*)&Bs[r * 64 + ((ua ^ (r & 7)) * 8)];
        }
#pragma unroll
        for (int i = 0; i < 4; i++)
#pragma unroll
          for (int j = 0; j < 4; j++)
            acc[i][j] = MFMA(a[i], b[j], acc[i][j]);
      }
      __syncthreads();
    }
    // z1 = relu(acc + h_rep)
#pragma unroll
    for (int i = 0; i < 4; i++) {
      int sample = (m0 + wm + i * 16) >> 4;
#pragma unroll
      for (int j = 0; j < 4; j++) {
        int col = n0 + wn + j * 16 + lm;
        float hv = h[(size_t)sample * 512 + col];
#pragma unroll
        for (int r = 0; r < 4; r++) {
          int row = wm + i * 16 + quad * 4 + r;
          smem[row * 128 + (col - n0)] = (bf16)fmaxf(acc[i][j][r] + hv, 0.f);
        }
      }
    }
    __syncthreads();
#pragma unroll
    for (int c = 0; c < 8; c++) {
      int ci = c * 256 + tid;
      int row = ci >> 4, col8 = (ci & 15) * 8;
      *(bf16x8*)&z1[(size_t)(m0 + row) * 512 + n0 + col8] = *(const bf16x8*)&smem[row * 128 + col8];
    }
  }
  gbar(&flags[256 + mt]);

  // ================= Phase C: z2 = relu(z1 @ W2 + b2) + q-head =============
  {
    f32x4 acc[4][4] = {};
    for (int k0 = 0; k0 < 512; k0 += 64) {
#pragma unroll
      for (int it = 0; it < 4; it++) {
        int idx = it * 256 + tid;
        int row = idx >> 3;
        int c = idx & 7;
        int cv8 = c ^ (row & 7);
        int kk = k0 + cv8 * 8;
        const bf16* ga = z1 + (size_t)(m0 + row) * 512 + kk;
        __builtin_amdgcn_global_load_lds(GL(ga), SH(&As[(idx & ~63) * 8]), 16, 0, 0);
        const bf16* gb = W2T + (size_t)(n0 + row) * 512 + kk;
        __builtin_amdgcn_global_load_lds(GL(gb), SH(&Bs[(idx & ~63) * 8]), 16, 0, 0);
      }
      __syncthreads();
#pragma unroll
      for (int ks = 0; ks < 2; ks++) {
        const int ua = quad + ks * 4;
        bf16x8 a[4], b[4];
#pragma unroll
        for (int i = 0; i < 4; i++) {
          int r = wm + lm + i * 16;
          a[i] = *(const bf16x8*)&As[r * 64 + ((ua ^ (r & 7)) * 8)];
        }
#pragma unroll
        for (int j = 0; j < 4; j++) {
          int r = wn + lm + j * 16;
          b[j] = *(const bf16x8*)&Bs[r * 64 + ((ua ^ (r & 7)) * 8)];
        }
#pragma unroll
        for (int i = 0; i < 4; i++)
#pragma unroll
          for (int j = 0; j < 4; j++)
            acc[i][j] = MFMA(a[i], b[j], acc[i][j]);
      }
      __syncthreads();
    }
#pragma unroll
    for (int i = 0; i < 4; i++)
#pragma unroll
      for (int j = 0; j < 4; j++) {
        int col = wn + j * 16 + lm;
        float bb = b2[n0 + col];
#pragma unroll
        for (int r = 0; r < 4; r++) {
          int row = wm + i * 16 + quad * 4 + r;
          smem[row * 128 + col] = (bf16)fmaxf(acc[i][j][r] + bb, 0.f);
        }
      }
    __syncthreads();
    int n = lane & 7;
    int kg = lane >> 3;
    float w3r[16];
#pragma unroll
    for (int i = 0; i < 16; i++) w3r[i] = W3[(size_t)(n0 + kg * 16 + i) * 8 + n];
    float bn = (n_idx == 0) ? b3[n] : 0.f;
    int rbase = wave * 32;
    for (int rr = 0; rr < 32; rr++) {
      const bf16* zr = &smem[(rbase + rr) * 128 + kg * 16];
      bf16x8 z0 = *(const bf16x8*)zr;
      bf16x8 z1v = *(const bf16x8*)(zr + 8);
      float v = 0.f;
#pragma unroll
      for (int i = 0; i < 8; i++) v += (float)z0[i] * w3r[i];
#pragma unroll
      for (int i = 0; i < 8; i++) v += (float)z1v[i] * w3r[8 + i];
      v += __shfl_down(v, 32);
      v += __shfl_down(v, 16);
      v += __shfl_down(v, 8);
      if (lane < 8) atomicAdd(&outq[(size_t)(m0 + rbase + rr) * 8 + n], v + bn);
    }
  }
}

extern "C" void kernel_launch(void* const* d_in, const int* in_sizes, int n_in,
                              void* d_out, int out_size, void* d_ws, size_t ws_size,
                              hipStream_t stream) {
  const float* obs    = (const float*)d_in[0];
  const float* W_pre  = (const float*)d_in[1];
  const float* b_pre  = (const float*)d_in[2];
  const float* W_gcn  = (const float*)d_in[3];
  const float* b_gcn  = (const float*)d_in[4];
  const float* W_post = (const float*)d_in[5];
  const float* b_post = (const float*)d_in[6];
  const float* W_loc  = (const float*)d_in[7];
  const float* b_loc  = (const float*)d_in[8];
  const float* W1     = (const float*)d_in[9];
  const float* b1     = (const float*)d_in[10];
  const float* W2     = (const float*)d_in[11];
  const float* b2     = (const float*)d_in[12];
  const float* W3     = (const float*)d_in[13];
  const float* b3     = (const float*)d_in[14];
  float* out = (float*)d_out;

  char* p = (char*)d_ws;
  auto alloc = [&](size_t bytes) { char* r = p; p += (bytes + 255) & ~(size_t)255; return r; };
  bf16* WpreLocT = (bf16*)alloc(384 * 128 * 2);
  float* biasPL  = (float*)alloc(384 * 4);
  bf16* Wg0T   = (bf16*)alloc(128 * 128 * 2);
  bf16* Wg1T   = (bf16*)alloc(128 * 128 * 2);
  bf16* WpostT = (bf16*)alloc(256 * 128 * 2);
  bf16* W1T    = (bf16*)alloc(512 * 512 * 2);
  bf16* W2T    = (bf16*)alloc(512 * 512 * 2);
  bf16* locB   = (bf16*)alloc((size_t)32768 * 256 * 2);
  float* hB    = (float*)alloc((size_t)2048 * 512 * 4);
  bf16* z1B    = (bf16*)alloc((size_t)32768 * 512 * 2);
  int* flags   = (int*)alloc(512 * 4);

  // P: weight prep + bias + d_out zero + flag zero
  prep_all<<<641, 256, 0, stream>>>(W1, W2, W1T, W2T,
                                    W_pre, W_loc, W_gcn, W_post,
                                    WpreLocT, Wg0T, Wg1T, WpostT,
                                    b_pre, b_loc, biasPL, out, flags);
  // F: whole network, one dispatch (per-m-tile group barriers)
  fused<<<1024, 256, 0, stream>>>(obs, WpreLocT, biasPL,
                                  Wg0T, Wg1T, WpostT, b_gcn, b_post,
                                  W1T, b1, W2T, b2, W3, b3,
                                  locB, hB, z1B, out, flags);
}

// Round 13
// 175.169 us; speedup vs baseline: 2.8652x; 2.8652x over previous
//
#include <hip/hip_runtime.h>
#include <hip/hip_bf16.h>
#include <stdint.h>

typedef __bf16 bf16;
typedef __bf16 bf16x4 __attribute__((ext_vector_type(4)));
typedef __bf16 bf16x8 __attribute__((ext_vector_type(8)));
typedef float f32x4 __attribute__((ext_vector_type(4)));

#define MFMA(a, b, c) __builtin_amdgcn_mfma_f32_16x16x32_bf16(a, b, c, 0, 0, 0)
#define GL(p) ((const __attribute__((address_space(1))) void*)(p))
#define SH(p) ((__attribute__((address_space(3))) void*)(p))

// ---- prep: W transposes (bf16), bias concat, zero d_out ----
__device__ inline void tp(const float* W, bf16* WT, int id, int shiftK, int N) {
  int K = 1 << shiftK;
  int n = id >> shiftK;
  int k = id & (K - 1);
  WT[id] = (bf16)W[(size_t)k * N + n];
}

__global__ __launch_bounds__(256) void prep_all(
    const float* __restrict__ W1, const float* __restrict__ W2,
    bf16* __restrict__ W1T, bf16* __restrict__ W2T,
    const float* __restrict__ Wpre, const float* __restrict__ Wloc,
    const float* __restrict__ Wgcn, const float* __restrict__ Wpost,
    bf16* __restrict__ WpreLocT, bf16* __restrict__ Wg0T, bf16* __restrict__ Wg1T,
    bf16* __restrict__ WpostT,
    const float* __restrict__ bpre, const float* __restrict__ bloc,
    float* __restrict__ biasPL, float* __restrict__ outq) {
  __shared__ bf16 tile[64 * 68];
  int blk = blockIdx.x;
  int tid = threadIdx.x;
  if (blk < 128) {                       // tiled transpose W1/W2 (512x512 each)
    const float* W = (blk < 64) ? W1 : W2;
    bf16* WT = (blk < 64) ? W1T : W2T;
    int t = blk & 63;
    int tk0 = (t >> 3) * 64, tn0 = (t & 7) * 64;
#pragma unroll
    for (int p = 0; p < 4; p++) {
      int kr = p * 16 + (tid >> 4), nc = (tid & 15) * 4;
      float4 f = *(const float4*)(W + (size_t)(tk0 + kr) * 512 + tn0 + nc);
      bf16x4 v; v[0] = (bf16)f.x; v[1] = (bf16)f.y; v[2] = (bf16)f.z; v[3] = (bf16)f.w;
      *(bf16x4*)&tile[kr * 68 + nc] = v;
    }
    __syncthreads();
#pragma unroll
    for (int p = 0; p < 4; p++) {
      int nr = p * 16 + (tid >> 4), kc = (tid & 15) * 4;
      bf16x4 v;
#pragma unroll
      for (int i = 0; i < 4; i++) v[i] = tile[(kc + i) * 68 + nr];
      *(bf16x4*)(WT + (size_t)(tn0 + nr) * 512 + tk0 + kc) = v;
    }
    return;
  }
  blk -= 128;
  if (blk < 448) {                       // small transposes
    int id = blk * 256 + tid;
    if (id < 16384) { tp(Wpre, WpreLocT, id, 7, 128); return; } id -= 16384;
    if (id < 32768) { tp(Wloc, WpreLocT + 16384, id, 7, 256); return; } id -= 32768;
    if (id < 16384) { tp(Wgcn, Wg0T, id, 7, 128); return; } id -= 16384;
    if (id < 16384) { tp(Wgcn + 16384, Wg1T, id, 7, 128); return; } id -= 16384;
    tp(Wpost, WpostT, id, 7, 256);
    return;
  }
  blk -= 448;
  if (blk == 0) {                        // bias concat
    if (tid < 128) biasPL[tid] = bpre[tid];
    biasPL[128 + tid] = bloc[tid];
    return;
  }
  blk -= 1;
  // zero d_out: 64 blocks x 256 threads x 4 float4 = 262144 floats
  float4 z = {0.f, 0.f, 0.f, 0.f};
#pragma unroll
  for (int i = 0; i < 4; i++)
    ((float4*)outq)[(size_t)blk * 1024 + i * 256 + tid] = z;
}

// ---- K1 + collapsed GCN chain + h-precompute, fused ----
// 768 blocks XCD-swizzled (3 n-siblings/m-tile). nt0: pre-GEMM -> pool ->
// 3-layer chain -> g (LDS only) -> h = g@W1a + b1 (fp32, global). nt1,2: loc.
// A staged inline from fp32 obs (swizzle invariant); B via global_load_lds.
__global__ __launch_bounds__(256, 4) void k1c(
    const float* __restrict__ obs, const bf16* __restrict__ WpreLocT,
    const float* __restrict__ biasPL,
    const bf16* __restrict__ Wg0T, const bf16* __restrict__ Wg1T,
    const bf16* __restrict__ WpostT, const float* __restrict__ b_gcn,
    const float* __restrict__ b_post,
    const bf16* __restrict__ W1T, const float* __restrict__ b1,
    bf16* __restrict__ loc, float* __restrict__ h) {
  __shared__ bf16 smem[16384];
  bf16* As = smem;
  bf16* Bs = smem + 8192;

  const int tid = threadIdx.x;
  const int id = blockIdx.x;
  const int s = id >> 3;
  const int n_idx = s % 3;
  const int m0 = ((id & 7) + 8 * (s / 3)) * 128;
  const int n0 = n_idx * 128;

  f32x4 acc[4][4] = {};
  const int lane = tid & 63, wave = tid >> 6;
  const int wm = (wave >> 1) * 64, wn = (wave & 1) * 64;
  const int lm = lane & 15, quad = lane >> 4;

  for (int k0 = 0; k0 < 128; k0 += 64) {
#pragma unroll
    for (int it = 0; it < 4; it++) {
      int idx = it * 256 + tid;
      int row = idx >> 3;
      int c = idx & 7;
      int cv8 = c ^ (row & 7);
      int kk = k0 + cv8 * 8;
      const float* src = obs + (size_t)(m0 + row) * 128 + kk;
      float4 f0 = *(const float4*)src;
      float4 f1 = *(const float4*)(src + 4);
      bf16x8 v;
      v[0] = (bf16)f0.x; v[1] = (bf16)f0.y; v[2] = (bf16)f0.z; v[3] = (bf16)f0.w;
      v[4] = (bf16)f1.x; v[5] = (bf16)f1.y; v[6] = (bf16)f1.z; v[7] = (bf16)f1.w;
      *(bf16x8*)&As[row * 64 + c * 8] = v;
      const bf16* gb = WpreLocT + (size_t)(n0 + row) * 128 + kk;
      __builtin_amdgcn_global_load_lds(GL(gb), SH(&Bs[(idx & ~63) * 8]), 16, 0, 0);
    }
    __syncthreads();
#pragma unroll
    for (int ks = 0; ks < 2; ks++) {
      const int ua = quad + ks * 4;
      bf16x8 a[4], b[4];
#pragma unroll
      for (int i = 0; i < 4; i++) {
        int r = wm + lm + i * 16;
        a[i] = *(const bf16x8*)&As[r * 64 + ((ua ^ (r & 7)) * 8)];
      }
#pragma unroll
      for (int j = 0; j < 4; j++) {
        int r = wn + lm + j * 16;
        b[j] = *(const bf16x8*)&Bs[r * 64 + ((ua ^ (r & 7)) * 8)];
      }
#pragma unroll
      for (int i = 0; i < 4; i++)
#pragma unroll
        for (int j = 0; j < 4; j++)
          acc[i][j] = MFMA(a[i], b[j], acc[i][j]);
    }
    __syncthreads();
  }

  if (n_idx == 0) {
    // pool into LDS xbar (rows 0..7 real, 8..15 zero)
    bf16* xs = smem;                  // 16 x 136
    bf16* x2 = smem + 2176;           // 16 x 136
    bf16* gS = smem + 4352;           // 16 x 264 (g tile, cols 0..255)
#pragma unroll
    for (int i = 0; i < 4; i++) {
      int sl = (wave >> 1) * 4 + i;
#pragma unroll
      for (int j = 0; j < 4; j++) {
        int col = wn + j * 16 + lm;
        float bb = biasPL[col];
        float v = 0.f;
#pragma unroll
        for (int r = 0; r < 4; r++) v += fmaxf(acc[i][j][r] + bb, 0.f);
        v += __shfl_xor(v, 16);
        v += __shfl_xor(v, 32);
        if (quad == 0) xs[sl * 136 + col] = (bf16)(v * 0.0625f);
        else if (quad == 1) xs[(8 + sl) * 136 + col] = (bf16)0.f;
      }
    }
    __syncthreads();
    {  // l0: xs -> x2
      f32x4 c2[2] = {};
#pragma unroll
      for (int ku = 0; ku < 4; ++ku) {
        bf16x8 a = *(const bf16x8*)&xs[lm * 136 + (ku * 4 + quad) * 8];
#pragma unroll
        for (int jn = 0; jn < 2; ++jn) {
          int col = (wave * 2 + jn) * 16 + lm;
          bf16x8 b = *(const bf16x8*)&Wg0T[(size_t)col * 128 + ku * 32 + quad * 8];
          c2[jn] = MFMA(a, b, c2[jn]);
        }
      }
      __syncthreads();
#pragma unroll
      for (int jn = 0; jn < 2; ++jn) {
        int col = (wave * 2 + jn) * 16 + lm;
        float bb = b_gcn[col];
#pragma unroll
        for (int r = 0; r < 4; ++r)
          x2[(quad * 4 + r) * 136 + col] = (bf16)fmaxf(c2[jn][r] + bb, 0.f);
      }
    }
    __syncthreads();
    {  // l1: x2 -> xs
      f32x4 c2[2] = {};
#pragma unroll
      for (int ku = 0; ku < 4; ++ku) {
        bf16x8 a = *(const bf16x8*)&x2[lm * 136 + (ku * 4 + quad) * 8];
#pragma unroll
        for (int jn = 0; jn < 2; ++jn) {
          int col = (wave * 2 + jn) * 16 + lm;
          bf16x8 b = *(const bf16x8*)&Wg1T[(size_t)col * 128 + ku * 32 + quad * 8];
          c2[jn] = MFMA(a, b, c2[jn]);
        }
      }
      __syncthreads();
#pragma unroll
      for (int jn = 0; jn < 2; ++jn) {
        int col = (wave * 2 + jn) * 16 + lm;
        float bb = b_gcn[128 + col];
#pragma unroll
        for (int r = 0; r < 4; ++r)
          xs[(quad * 4 + r) * 136 + col] = (bf16)fmaxf(c2[jn][r] + bb, 0.f);
      }
    }
    __syncthreads();
    {  // l2: xs -> gS (LDS, N=256)
      f32x4 c3[4] = {};
#pragma unroll
      for (int ku = 0; ku < 4; ++ku) {
        bf16x8 a = *(const bf16x8*)&xs[lm * 136 + (ku * 4 + quad) * 8];
#pragma unroll
        for (int jn = 0; jn < 4; ++jn) {
          int col = (wave * 4 + jn) * 16 + lm;
          bf16x8 b = *(const bf16x8*)&WpostT[(size_t)col * 128 + ku * 32 + quad * 8];
          c3[jn] = MFMA(a, b, c3[jn]);
        }
      }
#pragma unroll
      for (int jn = 0; jn < 4; ++jn) {
        int col = (wave * 4 + jn) * 16 + lm;
        float bb = b_post[col];
#pragma unroll
        for (int r = 0; r < 4; ++r)
          gS[(quad * 4 + r) * 264 + col] = (bf16)fmaxf(c3[jn][r] + bb, 0.f);
      }
    }
    __syncthreads();
    {  // h = g @ W1a + b1  (M=16 frag, rows 0..7 real; N=512; K=256; fp32 out)
      f32x4 hacc[8] = {};
#pragma unroll
      for (int ku = 0; ku < 8; ++ku) {
        bf16x8 a = *(const bf16x8*)&gS[lm * 264 + ku * 32 + quad * 8];
#pragma unroll
        for (int jn = 0; jn < 8; ++jn) {
          int col = (wave * 8 + jn) * 16 + lm;
          bf16x8 b = *(const bf16x8*)&W1T[(size_t)col * 512 + ku * 32 + quad * 8];
          hacc[jn] = MFMA(a, b, hacc[jn]);
        }
      }
      int sample0 = m0 >> 4;
#pragma unroll
      for (int jn = 0; jn < 8; ++jn) {
        int col = (wave * 8 + jn) * 16 + lm;
        float bb = b1[col];
#pragma unroll
        for (int r = 0; r < 4; ++r) {
          int row = quad * 4 + r;
          if (row < 8)
            h[(size_t)(sample0 + row) * 512 + col] = hacc[jn][r] + bb;
        }
      }
    }
  } else {
    // loc: coalesced store via LDS tile
#pragma unroll
    for (int i = 0; i < 4; i++)
#pragma unroll
      for (int j = 0; j < 4; j++) {
        int col = wn + j * 16 + lm;
        float bb = biasPL[n0 + col];
#pragma unroll
        for (int r = 0; r < 4; r++) {
          int row = wm + i * 16 + quad * 4 + r;
          smem[row * 128 + col] = (bf16)fmaxf(acc[i][j][r] + bb, 0.f);
        }
      }
    __syncthreads();
    const int coff = n0 - 128;
#pragma unroll
    for (int c = 0; c < 8; c++) {
      int ci = c * 256 + tid;
      int row = ci >> 4, col8 = (ci & 15) * 8;
      *(bf16x8*)&loc[(size_t)(m0 + row) * 256 + coff + col8] = *(const bf16x8*)&smem[row * 128 + col8];
    }
  }
}

// ---- 128x128 bf16 MFMA GEMM (K3/K4), m97-staged, XCD-swizzled ----
// HREP (K3): A = loc [M,256], B = W1T k-half 256.., epilogue relu(acc + h_rep)
//            (h already contains b1), C store.
// !HREP (K4): A = z1 [M,512], B = W2T, QFUSE epilogue: q-head, atomic out.
template <bool HREP>
__global__ __launch_bounds__(256, 4) void gemm_k(
    const bf16* __restrict__ Ab, const bf16* __restrict__ BT,
    const float* __restrict__ bias, const float* __restrict__ hrep,
    bf16* __restrict__ C,
    const float* __restrict__ W3, const float* __restrict__ b3,
    float* __restrict__ outq) {
  __shared__ bf16 smem[16384];
  bf16* As = smem;
  bf16* Bs = smem + 8192;

  const int tid = threadIdx.x;
  const int id = blockIdx.x;
  const int s = id >> 3;
  const int n_idx = s & 3;
  const int m0 = ((id & 7) + 8 * (s >> 2)) * 128;
  const int n0 = n_idx * 128;

  f32x4 acc[4][4] = {};
  const int lane = tid & 63, wave = tid >> 6;
  const int wm = (wave >> 1) * 64, wn = (wave & 1) * 64;
  const int lm = lane & 15, quad = lane >> 4;

  const int KTOT = HREP ? 256 : 512;
  for (int k0 = 0; k0 < KTOT; k0 += 64) {
#pragma unroll
    for (int it = 0; it < 4; it++) {
      int idx = it * 256 + tid;
      int row = idx >> 3;
      int c = idx & 7;
      int cv8 = c ^ (row & 7);
      int kk = k0 + cv8 * 8;
      const bf16* ga = HREP ? (Ab + (size_t)(m0 + row) * 256 + kk)
                            : (Ab + (size_t)(m0 + row) * 512 + kk);
      __builtin_amdgcn_global_load_lds(GL(ga), SH(&As[(idx & ~63) * 8]), 16, 0, 0);
      const bf16* gb = HREP ? (BT + (size_t)(n0 + row) * 512 + 256 + kk)
                            : (BT + (size_t)(n0 + row) * 512 + kk);
      __builtin_amdgcn_global_load_lds(GL(gb), SH(&Bs[(idx & ~63) * 8]), 16, 0, 0);
    }
    __syncthreads();
#pragma unroll
    for (int ks = 0; ks < 2; ks++) {
      const int ua = quad + ks * 4;
      bf16x8 a[4], b[4];
#pragma unroll
      for (int i = 0; i < 4; i++) {
        int r = wm + lm + i * 16;
        a[i] = *(const bf16x8*)&As[r * 64 + ((ua ^ (r & 7)) * 8)];
      }
#pragma unroll
      for (int j = 0; j < 4; j++) {
        int r = wn + lm + j * 16;
        b[j] = *(const bf16x8*)&Bs[r * 64 + ((ua ^ (r & 7)) * 8)];
      }
#pragma unroll
      for (int i = 0; i < 4; i++)
#pragma unroll
        for (int j = 0; j < 4; j++)
          acc[i][j] = MFMA(a[i], b[j], acc[i][j]);
    }
    __syncthreads();
  }

  if (HREP) {
    // z1 = relu(acc + h_rep); h indexed by sample (one load per frag per lane)
#pragma unroll
    for (int i = 0; i < 4; i++) {
      int sample = (m0 + wm + i * 16) >> 4;
#pragma unroll
      for (int j = 0; j < 4; j++) {
        int col = n0 + wn + j * 16 + lm;
        float hv = hrep[(size_t)sample * 512 + col];
#pragma unroll
        for (int r = 0; r < 4; r++) {
          int row = wm + i * 16 + quad * 4 + r;
          smem[row * 128 + (col - n0)] = (bf16)fmaxf(acc[i][j][r] + hv, 0.f);
        }
      }
    }
    __syncthreads();
#pragma unroll
    for (int c = 0; c < 8; c++) {
      int ci = c * 256 + tid;
      int row = ci >> 4, col8 = (ci & 15) * 8;
      *(bf16x8*)&C[(size_t)(m0 + row) * 512 + n0 + col8] = *(const bf16x8*)&smem[row * 128 + col8];
    }
  } else {
#pragma unroll
    for (int i = 0; i < 4; i++)
#pragma unroll
      for (int j = 0; j < 4; j++) {
        int col = wn + j * 16 + lm;
        float bb = bias[n0 + col];
#pragma unroll
        for (int r = 0; r < 4; r++) {
          int row = wm + i * 16 + quad * 4 + r;
          smem[row * 128 + col] = (bf16)fmaxf(acc[i][j][r] + bb, 0.f);
        }
      }
    __syncthreads();
    int n = lane & 7;
    int kg = lane >> 3;
    float w3r[16];
#pragma unroll
    for (int i = 0; i < 16; i++) w3r[i] = W3[(size_t)(n0 + kg * 16 + i) * 8 + n];
    float bn = (n_idx == 0) ? b3[n] : 0.f;
    int rbase = wave * 32;
    for (int rr = 0; rr < 32; rr++) {
      const bf16* zr = &smem[(rbase + rr) * 128 + kg * 16];
      bf16x8 z0 = *(const bf16x8*)zr;
      bf16x8 z1v = *(const bf16x8*)(zr + 8);
      float v = 0.f;
#pragma unroll
      for (int i = 0; i < 8; i++) v += (float)z0[i] * w3r[i];
#pragma unroll
      for (int i = 0; i < 8; i++) v += (float)z1v[i] * w3r[8 + i];
      v += __shfl_down(v, 32);
      v += __shfl_down(v, 16);
      v += __shfl_down(v, 8);
      if (lane < 8) atomicAdd(&outq[(size_t)(m0 + rbase + rr) * 8 + n], v + bn);
    }
  }
}

extern "C" void kernel_launch(void* const* d_in, const int* in_sizes, int n_in,
                              void* d_out, int out_size, void* d_ws, size_t ws_size,
                              hipStream_t stream) {
  const float* obs    = (const float*)d_in[0];
  const float* W_pre  = (const float*)d_in[1];
  const float* b_pre  = (const float*)d_in[2];
  const float* W_gcn  = (const float*)d_in[3];
  const float* b_gcn  = (const float*)d_in[4];
  const float* W_post = (const float*)d_in[5];
  const float* b_post = (const float*)d_in[6];
  const float* W_loc  = (const float*)d_in[7];
  const float* b_loc  = (const float*)d_in[8];
  const float* W1     = (const float*)d_in[9];
  const float* b1     = (const float*)d_in[10];
  const float* W2     = (const float*)d_in[11];
  const float* b2     = (const float*)d_in[12];
  const float* W3     = (const float*)d_in[13];
  const float* b3     = (const float*)d_in[14];
  float* out = (float*)d_out;

  char* p = (char*)d_ws;
  auto alloc = [&](size_t bytes) { char* r = p; p += (bytes + 255) & ~(size_t)255; return r; };
  bf16* WpreLocT = (bf16*)alloc(384 * 128 * 2);
  float* biasPL  = (float*)alloc(384 * 4);
  bf16* Wg0T   = (bf16*)alloc(128 * 128 * 2);
  bf16* Wg1T   = (bf16*)alloc(128 * 128 * 2);
  bf16* WpostT = (bf16*)alloc(256 * 128 * 2);
  bf16* W1T    = (bf16*)alloc(512 * 512 * 2);
  bf16* W2T    = (bf16*)alloc(512 * 512 * 2);
  bf16* locB   = (bf16*)alloc((size_t)32768 * 256 * 2);
  float* hB    = (float*)alloc((size_t)2048 * 512 * 4);
  bf16* z1B    = (bf16*)alloc((size_t)32768 * 512 * 2);

  // P: weight prep + bias + d_out zero (641 blocks)
  prep_all<<<641, 256, 0, stream>>>(W1, W2, W1T, W2T,
                                    W_pre, W_loc, W_gcn, W_post,
                                    WpreLocT, Wg0T, Wg1T, WpostT,
                                    b_pre, b_loc, biasPL, out);
  // K1+chain+h: pre(pool->chain->g->h) + loc
  k1c<<<768, 256, 0, stream>>>(obs, WpreLocT, biasPL,
                               Wg0T, Wg1T, WpostT, b_gcn, b_post,
                               W1T, b1, locB, hB);
  // K3: z1 = relu(loc @ W1b + h_rep)   (K=256 — g-half precomputed in k1c)
  gemm_k<true><<<1024, 256, 0, stream>>>(locB, W1T, nullptr, hB, z1B,
                                         nullptr, nullptr, nullptr);
  // K4: z2 = relu(z1 @ W2 + b2) fused q-head, atomic accumulate into out
  gemm_k<false><<<1024, 256, 0, stream>>>(z1B, W2T, b2, nullptr, nullptr,
                                          W3, b3, out);
}

// Round 14
// 163.423 us; speedup vs baseline: 3.0711x; 1.0719x over previous
//
#include <hip/hip_runtime.h>
#include <hip/hip_bf16.h>
#include <stdint.h>

typedef __bf16 bf16;
typedef __bf16 bf16x4 __attribute__((ext_vector_type(4)));
typedef __bf16 bf16x8 __attribute__((ext_vector_type(8)));
typedef float f32x4 __attribute__((ext_vector_type(4)));

#define MFMA(a, b, c) __builtin_amdgcn_mfma_f32_16x16x32_bf16(a, b, c, 0, 0, 0)
#define GL(p) ((const __attribute__((address_space(1))) void*)(p))
#define SH(p) ((__attribute__((address_space(3))) void*)(p))

// ---- prep: W transposes (bf16), bias concat, zero d_out ----
__device__ inline void tp(const float* W, bf16* WT, int id, int shiftK, int N) {
  int K = 1 << shiftK;
  int n = id >> shiftK;
  int k = id & (K - 1);
  WT[id] = (bf16)W[(size_t)k * N + n];
}

__global__ __launch_bounds__(256) void prep_all(
    const float* __restrict__ W1, const float* __restrict__ W2,
    bf16* __restrict__ W1T, bf16* __restrict__ W2T,
    const float* __restrict__ Wpre, const float* __restrict__ Wloc,
    const float* __restrict__ Wgcn, const float* __restrict__ Wpost,
    bf16* __restrict__ WpreLocT, bf16* __restrict__ Wg0T, bf16* __restrict__ Wg1T,
    bf16* __restrict__ WpostT,
    const float* __restrict__ bpre, const float* __restrict__ bloc,
    float* __restrict__ biasPL, float* __restrict__ outq) {
  __shared__ bf16 tile[64 * 68];
  int blk = blockIdx.x;
  int tid = threadIdx.x;
  if (blk < 128) {                       // tiled transpose W1/W2 (512x512 each)
    const float* W = (blk < 64) ? W1 : W2;
    bf16* WT = (blk < 64) ? W1T : W2T;
    int t = blk & 63;
    int tk0 = (t >> 3) * 64, tn0 = (t & 7) * 64;
#pragma unroll
    for (int p = 0; p < 4; p++) {
      int kr = p * 16 + (tid >> 4), nc = (tid & 15) * 4;
      float4 f = *(const float4*)(W + (size_t)(tk0 + kr) * 512 + tn0 + nc);
      bf16x4 v; v[0] = (bf16)f.x; v[1] = (bf16)f.y; v[2] = (bf16)f.z; v[3] = (bf16)f.w;
      *(bf16x4*)&tile[kr * 68 + nc] = v;
    }
    __syncthreads();
#pragma unroll
    for (int p = 0; p < 4; p++) {
      int nr = p * 16 + (tid >> 4), kc = (tid & 15) * 4;
      bf16x4 v;
#pragma unroll
      for (int i = 0; i < 4; i++) v[i] = tile[(kc + i) * 68 + nr];
      *(bf16x4*)(WT + (size_t)(tn0 + nr) * 512 + tk0 + kc) = v;
    }
    return;
  }
  blk -= 128;
  if (blk < 448) {                       // small transposes
    int id = blk * 256 + tid;
    if (id < 16384) { tp(Wpre, WpreLocT, id, 7, 128); return; } id -= 16384;
    if (id < 32768) { tp(Wloc, WpreLocT + 16384, id, 7, 256); return; } id -= 32768;
    if (id < 16384) { tp(Wgcn, Wg0T, id, 7, 128); return; } id -= 16384;
    if (id < 16384) { tp(Wgcn + 16384, Wg1T, id, 7, 128); return; } id -= 16384;
    tp(Wpost, WpostT, id, 7, 256);
    return;
  }
  blk -= 448;
  if (blk == 0) {                        // bias concat
    if (tid < 128) biasPL[tid] = bpre[tid];
    biasPL[128 + tid] = bloc[tid];
    return;
  }
  blk -= 1;
  // zero d_out: 64 blocks x 256 threads x 4 float4 = 262144 floats
  float4 z = {0.f, 0.f, 0.f, 0.f};
#pragma unroll
  for (int i = 0; i < 4; i++)
    ((float4*)outq)[(size_t)blk * 1024 + i * 256 + tid] = z;
}

// ---- K1 + collapsed GCN chain + h-precompute, fused (unchanged champion) ----
__global__ __launch_bounds__(256, 4) void k1c(
    const float* __restrict__ obs, const bf16* __restrict__ WpreLocT,
    const float* __restrict__ biasPL,
    const bf16* __restrict__ Wg0T, const bf16* __restrict__ Wg1T,
    const bf16* __restrict__ WpostT, const float* __restrict__ b_gcn,
    const float* __restrict__ b_post,
    const bf16* __restrict__ W1T, const float* __restrict__ b1,
    bf16* __restrict__ loc, float* __restrict__ h) {
  __shared__ bf16 smem[16384];
  bf16* As = smem;
  bf16* Bs = smem + 8192;

  const int tid = threadIdx.x;
  const int id = blockIdx.x;
  const int s = id >> 3;
  const int n_idx = s % 3;
  const int m0 = ((id & 7) + 8 * (s / 3)) * 128;
  const int n0 = n_idx * 128;

  f32x4 acc[4][4] = {};
  const int lane = tid & 63, wave = tid >> 6;
  const int wm = (wave >> 1) * 64, wn = (wave & 1) * 64;
  const int lm = lane & 15, quad = lane >> 4;

  for (int k0 = 0; k0 < 128; k0 += 64) {
#pragma unroll
    for (int it = 0; it < 4; it++) {
      int idx = it * 256 + tid;
      int row = idx >> 3;
      int c = idx & 7;
      int cv8 = c ^ (row & 7);
      int kk = k0 + cv8 * 8;
      const float* src = obs + (size_t)(m0 + row) * 128 + kk;
      float4 f0 = *(const float4*)src;
      float4 f1 = *(const float4*)(src + 4);
      bf16x8 v;
      v[0] = (bf16)f0.x; v[1] = (bf16)f0.y; v[2] = (bf16)f0.z; v[3] = (bf16)f0.w;
      v[4] = (bf16)f1.x; v[5] = (bf16)f1.y; v[6] = (bf16)f1.z; v[7] = (bf16)f1.w;
      *(bf16x8*)&As[row * 64 + c * 8] = v;
      const bf16* gb = WpreLocT + (size_t)(n0 + row) * 128 + kk;
      __builtin_amdgcn_global_load_lds(GL(gb), SH(&Bs[(idx & ~63) * 8]), 16, 0, 0);
    }
    __syncthreads();
#pragma unroll
    for (int ks = 0; ks < 2; ks++) {
      const int ua = quad + ks * 4;
      bf16x8 a[4], b[4];
#pragma unroll
      for (int i = 0; i < 4; i++) {
        int r = wm + lm + i * 16;
        a[i] = *(const bf16x8*)&As[r * 64 + ((ua ^ (r & 7)) * 8)];
      }
#pragma unroll
      for (int j = 0; j < 4; j++) {
        int r = wn + lm + j * 16;
        b[j] = *(const bf16x8*)&Bs[r * 64 + ((ua ^ (r & 7)) * 8)];
      }
#pragma unroll
      for (int i = 0; i < 4; i++)
#pragma unroll
        for (int j = 0; j < 4; j++)
          acc[i][j] = MFMA(a[i], b[j], acc[i][j]);
    }
    __syncthreads();
  }

  if (n_idx == 0) {
    bf16* xs = smem;                  // 16 x 136
    bf16* x2 = smem + 2176;           // 16 x 136
    bf16* gS = smem + 4352;           // 16 x 264
#pragma unroll
    for (int i = 0; i < 4; i++) {
      int sl = (wave >> 1) * 4 + i;
#pragma unroll
      for (int j = 0; j < 4; j++) {
        int col = wn + j * 16 + lm;
        float bb = biasPL[col];
        float v = 0.f;
#pragma unroll
        for (int r = 0; r < 4; r++) v += fmaxf(acc[i][j][r] + bb, 0.f);
        v += __shfl_xor(v, 16);
        v += __shfl_xor(v, 32);
        if (quad == 0) xs[sl * 136 + col] = (bf16)(v * 0.0625f);
        else if (quad == 1) xs[(8 + sl) * 136 + col] = (bf16)0.f;
      }
    }
    __syncthreads();
    {  // l0: xs -> x2
      f32x4 c2[2] = {};
#pragma unroll
      for (int ku = 0; ku < 4; ++ku) {
        bf16x8 a = *(const bf16x8*)&xs[lm * 136 + (ku * 4 + quad) * 8];
#pragma unroll
        for (int jn = 0; jn < 2; ++jn) {
          int col = (wave * 2 + jn) * 16 + lm;
          bf16x8 b = *(const bf16x8*)&Wg0T[(size_t)col * 128 + ku * 32 + quad * 8];
          c2[jn] = MFMA(a, b, c2[jn]);
        }
      }
      __syncthreads();
#pragma unroll
      for (int jn = 0; jn < 2; ++jn) {
        int col = (wave * 2 + jn) * 16 + lm;
        float bb = b_gcn[col];
#pragma unroll
        for (int r = 0; r < 4; ++r)
          x2[(quad * 4 + r) * 136 + col] = (bf16)fmaxf(c2[jn][r] + bb, 0.f);
      }
    }
    __syncthreads();
    {  // l1: x2 -> xs
      f32x4 c2[2] = {};
#pragma unroll
      for (int ku = 0; ku < 4; ++ku) {
        bf16x8 a = *(const bf16x8*)&x2[lm * 136 + (ku * 4 + quad) * 8];
#pragma unroll
        for (int jn = 0; jn < 2; ++jn) {
          int col = (wave * 2 + jn) * 16 + lm;
          bf16x8 b = *(const bf16x8*)&Wg1T[(size_t)col * 128 + ku * 32 + quad * 8];
          c2[jn] = MFMA(a, b, c2[jn]);
        }
      }
      __syncthreads();
#pragma unroll
      for (int jn = 0; jn < 2; ++jn) {
        int col = (wave * 2 + jn) * 16 + lm;
        float bb = b_gcn[128 + col];
#pragma unroll
        for (int r = 0; r < 4; ++r)
          xs[(quad * 4 + r) * 136 + col] = (bf16)fmaxf(c2[jn][r] + bb, 0.f);
      }
    }
    __syncthreads();
    {  // l2: xs -> gS
      f32x4 c3[4] = {};
#pragma unroll
      for (int ku = 0; ku < 4; ++ku) {
        bf16x8 a = *(const bf16x8*)&xs[lm * 136 + (ku * 4 + quad) * 8];
#pragma unroll
        for (int jn = 0; jn < 4; ++jn) {
          int col = (wave * 4 + jn) * 16 + lm;
          bf16x8 b = *(const bf16x8*)&WpostT[(size_t)col * 128 + ku * 32 + quad * 8];
          c3[jn] = MFMA(a, b, c3[jn]);
        }
      }
#pragma unroll
      for (int jn = 0; jn < 4; ++jn) {
        int col = (wave * 4 + jn) * 16 + lm;
        float bb = b_post[col];
#pragma unroll
        for (int r = 0; r < 4; ++r)
          gS[(quad * 4 + r) * 264 + col] = (bf16)fmaxf(c3[jn][r] + bb, 0.f);
      }
    }
    __syncthreads();
    {  // h = g @ W1a + b1
      f32x4 hacc[8] = {};
#pragma unroll
      for (int ku = 0; ku < 8; ++ku) {
        bf16x8 a = *(const bf16x8*)&gS[lm * 264 + ku * 32 + quad * 8];
#pragma unroll
        for (int jn = 0; jn < 8; ++jn) {
          int col = (wave * 8 + jn) * 16 + lm;
          bf16x8 b = *(const bf16x8*)&W1T[(size_t)col * 512 + ku * 32 + quad * 8];
          hacc[jn] = MFMA(a, b, hacc[jn]);
        }
      }
      int sample0 = m0 >> 4;
#pragma unroll
      for (int jn = 0; jn < 8; ++jn) {
        int col = (wave * 8 + jn) * 16 + lm;
        float bb = b1[col];
#pragma unroll
        for (int r = 0; r < 4; ++r) {
          int row = quad * 4 + r;
          if (row < 8)
            h[(size_t)(sample0 + row) * 512 + col] = hacc[jn][r] + bb;
        }
      }
    }
  } else {
#pragma unroll
    for (int i = 0; i < 4; i++)
#pragma unroll
      for (int j = 0; j < 4; j++) {
        int col = wn + j * 16 + lm;
        float bb = biasPL[n0 + col];
#pragma unroll
        for (int r = 0; r < 4; r++) {
          int row = wm + i * 16 + quad * 4 + r;
          smem[row * 128 + col] = (bf16)fmaxf(acc[i][j][r] + bb, 0.f);
        }
      }
    __syncthreads();
    const int coff = n0 - 128;
#pragma unroll
    for (int c = 0; c < 8; c++) {
      int ci = c * 256 + tid;
      int row = ci >> 4, col8 = (ci & 15) * 8;
      *(bf16x8*)&loc[(size_t)(m0 + row) * 256 + coff + col8] = *(const bf16x8*)&smem[row * 128 + col8];
    }
  }
}

// ---- K3/K4: 128x128 GEMM, BK=32, explicit LDS double-buffer ----
// One barrier per k-iter: stage(i+1, other buf) -> compute(i) -> barrier.
// The vmcnt(0) drain before each barrier lands AFTER a full compute phase has
// covered the DMA latency (anti-convoy). Swizzle: phys chunk c of row r holds
// logical chunk c ^ ((r>>1)&3); 2-way bank aliasing only (b128 minimum).
// HREP (K3): A = loc [M,256], B = W1T k-half, epilogue relu(acc + h_rep).
// !HREP (K4): A = z1 [M,512], B = W2T, q-head epilogue, atomic out.
template <bool HREP>
__global__ __launch_bounds__(256, 4) void gemm_k(
    const bf16* __restrict__ Ab, const bf16* __restrict__ BT,
    const float* __restrict__ bias, const float* __restrict__ hrep,
    bf16* __restrict__ C,
    const float* __restrict__ W3, const float* __restrict__ b3,
    float* __restrict__ outq) {
  __shared__ bf16 smem[16384];   // 2 x (A 4096 + B 4096)

  const int tid = threadIdx.x;
  const int id = blockIdx.x;
  const int s = id >> 3;
  const int n_idx = s & 3;
  const int m0 = ((id & 7) + 8 * (s >> 2)) * 128;
  const int n0 = n_idx * 128;

  f32x4 acc[4][4] = {};
  const int lane = tid & 63, wave = tid >> 6;
  const int wm = (wave >> 1) * 64, wn = (wave & 1) * 64;
  const int lm = lane & 15, quad = lane >> 4;

  auto stage = [&](int kt, int buf) {
    bf16* Ad = smem + buf * 8192;
    bf16* Bd = smem + buf * 8192 + 4096;
    int k0 = kt * 32;
#pragma unroll
    for (int it = 0; it < 2; it++) {
      int idx = it * 256 + tid;        // 512 chunks of 16B per matrix
      int row = idx >> 2;
      int c = idx & 3;
      int cv = c ^ ((row >> 1) & 3);
      int kk = k0 + cv * 8;
      const bf16* ga = HREP ? (Ab + (size_t)(m0 + row) * 256 + kk)
                            : (Ab + (size_t)(m0 + row) * 512 + kk);
      __builtin_amdgcn_global_load_lds(GL(ga), SH(&Ad[(idx & ~63) * 8]), 16, 0, 0);
      const bf16* gb = HREP ? (BT + (size_t)(n0 + row) * 512 + 256 + kk)
                            : (BT + (size_t)(n0 + row) * 512 + kk);
      __builtin_amdgcn_global_load_lds(GL(gb), SH(&Bd[(idx & ~63) * 8]), 16, 0, 0);
    }
  };

  auto compute = [&](int buf) {
    const bf16* Ar = smem + buf * 8192;
    const bf16* Br = smem + buf * 8192 + 4096;
    bf16x8 a[4], b[4];
#pragma unroll
    for (int i = 0; i < 4; i++) {
      int r = wm + lm + i * 16;
      a[i] = *(const bf16x8*)&Ar[r * 32 + ((quad ^ ((r >> 1) & 3)) * 8)];
    }
#pragma unroll
    for (int j = 0; j < 4; j++) {
      int r = wn + lm + j * 16;
      b[j] = *(const bf16x8*)&Br[r * 32 + ((quad ^ ((r >> 1) & 3)) * 8)];
    }
#pragma unroll
    for (int i = 0; i < 4; i++)
#pragma unroll
      for (int j = 0; j < 4; j++)
        acc[i][j] = MFMA(a[i], b[j], acc[i][j]);
  };

  const int NIT = HREP ? 8 : 16;
  stage(0, 0);
  __syncthreads();
#pragma unroll 2
  for (int i = 0; i < NIT; ++i) {
    if (i + 1 < NIT) stage(i + 1, (i + 1) & 1);   // prefetch overlaps compute
    compute(i & 1);
    __syncthreads();                               // drains prefetch post-compute
  }

  if (HREP) {
    // z1 = relu(acc + h_rep); h indexed by sample
#pragma unroll
    for (int i = 0; i < 4; i++) {
      int sample = (m0 + wm + i * 16) >> 4;
#pragma unroll
      for (int j = 0; j < 4; j++) {
        int col = n0 + wn + j * 16 + lm;
        float hv = hrep[(size_t)sample * 512 + col];
#pragma unroll
        for (int r = 0; r < 4; r++) {
          int row = wm + i * 16 + quad * 4 + r;
          smem[row * 128 + (col - n0)] = (bf16)fmaxf(acc[i][j][r] + hv, 0.f);
        }
      }
    }
    __syncthreads();
#pragma unroll
    for (int c = 0; c < 8; c++) {
      int ci = c * 256 + tid;
      int row = ci >> 4, col8 = (ci & 15) * 8;
      *(bf16x8*)&C[(size_t)(m0 + row) * 512 + n0 + col8] = *(const bf16x8*)&smem[row * 128 + col8];
    }
  } else {
#pragma unroll
    for (int i = 0; i < 4; i++)
#pragma unroll
      for (int j = 0; j < 4; j++) {
        int col = wn + j * 16 + lm;
        float bb = bias[n0 + col];
#pragma unroll
        for (int r = 0; r < 4; r++) {
          int row = wm + i * 16 + quad * 4 + r;
          smem[row * 128 + col] = (bf16)fmaxf(acc[i][j][r] + bb, 0.f);
        }
      }
    __syncthreads();
    int n = lane & 7;
    int kg = lane >> 3;
    float w3r[16];
#pragma unroll
    for (int i = 0; i < 16; i++) w3r[i] = W3[(size_t)(n0 + kg * 16 + i) * 8 + n];
    float bn = (n_idx == 0) ? b3[n] : 0.f;
    int rbase = wave * 32;
    for (int rr = 0; rr < 32; rr++) {
      const bf16* zr = &smem[(rbase + rr) * 128 + kg * 16];
      bf16x8 z0 = *(const bf16x8*)zr;
      bf16x8 z1v = *(const bf16x8*)(zr + 8);
      float v = 0.f;
#pragma unroll
      for (int i = 0; i < 8; i++) v += (float)z0[i] * w3r[i];
#pragma unroll
      for (int i = 0; i < 8; i++) v += (float)z1v[i] * w3r[8 + i];
      v += __shfl_down(v, 32);
      v += __shfl_down(v, 16);
      v += __shfl_down(v, 8);
      if (lane < 8) atomicAdd(&outq[(size_t)(m0 + rbase + rr) * 8 + n], v + bn);
    }
  }
}

extern "C" void kernel_launch(void* const* d_in, const int* in_sizes, int n_in,
                              void* d_out, int out_size, void* d_ws, size_t ws_size,
                              hipStream_t stream) {
  const float* obs    = (const float*)d_in[0];
  const float* W_pre  = (const float*)d_in[1];
  const float* b_pre  = (const float*)d_in[2];
  const float* W_gcn  = (const float*)d_in[3];
  const float* b_gcn  = (const float*)d_in[4];
  const float* W_post = (const float*)d_in[5];
  const float* b_post = (const float*)d_in[6];
  const float* W_loc  = (const float*)d_in[7];
  const float* b_loc  = (const float*)d_in[8];
  const float* W1     = (const float*)d_in[9];
  const float* b1     = (const float*)d_in[10];
  const float* W2     = (const float*)d_in[11];
  const float* b2     = (const float*)d_in[12];
  const float* W3     = (const float*)d_in[13];
  const float* b3     = (const float*)d_in[14];
  float* out = (float*)d_out;

  char* p = (char*)d_ws;
  auto alloc = [&](size_t bytes) { char* r = p; p += (bytes + 255) & ~(size_t)255; return r; };
  bf16* WpreLocT = (bf16*)alloc(384 * 128 * 2);
  float* biasPL  = (float*)alloc(384 * 4);
  bf16* Wg0T   = (bf16*)alloc(128 * 128 * 2);
  bf16* Wg1T   = (bf16*)alloc(128 * 128 * 2);
  bf16* WpostT = (bf16*)alloc(256 * 128 * 2);
  bf16* W1T    = (bf16*)alloc(512 * 512 * 2);
  bf16* W2T    = (bf16*)alloc(512 * 512 * 2);
  bf16* locB   = (bf16*)alloc((size_t)32768 * 256 * 2);
  float* hB    = (float*)alloc((size_t)2048 * 512 * 4);
  bf16* z1B    = (bf16*)alloc((size_t)32768 * 512 * 2);

  // P: weight prep + bias + d_out zero
  prep_all<<<641, 256, 0, stream>>>(W1, W2, W1T, W2T,
                                    W_pre, W_loc, W_gcn, W_post,
                                    WpreLocT, Wg0T, Wg1T, WpostT,
                                    b_pre, b_loc, biasPL, out);
  // K1+chain+h
  k1c<<<768, 256, 0, stream>>>(obs, WpreLocT, biasPL,
                               Wg0T, Wg1T, WpostT, b_gcn, b_post,
                               W1T, b1, locB, hB);
  // K3: z1 = relu(loc @ W1b + h_rep), K=256, double-buffered
  gemm_k<true><<<1024, 256, 0, stream>>>(locB, W1T, nullptr, hB, z1B,
                                         nullptr, nullptr, nullptr);
  // K4: z2 = relu(z1 @ W2 + b2) + q-head, K=512, double-buffered
  gemm_k<false><<<1024, 256, 0, stream>>>(z1B, W2T, b2, nullptr, nullptr,
                                          W3, b3, out);
}

// Round 15
// 161.232 us; speedup vs baseline: 3.1129x; 1.0136x over previous
//
#include <hip/hip_runtime.h>
#include <hip/hip_bf16.h>
#include <stdint.h>

typedef __bf16 bf16;
typedef __bf16 bf16x4 __attribute__((ext_vector_type(4)));
typedef __bf16 bf16x8 __attribute__((ext_vector_type(8)));
typedef float f32x4 __attribute__((ext_vector_type(4)));

#define MFMA(a, b, c) __builtin_amdgcn_mfma_f32_16x16x32_bf16(a, b, c, 0, 0, 0)
#define GL(p) ((const __attribute__((address_space(1))) void*)(p))
#define SH(p) ((__attribute__((address_space(3))) void*)(p))

// ---- prep: W transposes (bf16), bias concat, zero d_out ----
__device__ inline void tp(const float* W, bf16* WT, int id, int shiftK, int N) {
  int K = 1 << shiftK;
  int n = id >> shiftK;
  int k = id & (K - 1);
  WT[id] = (bf16)W[(size_t)k * N + n];
}

__global__ __launch_bounds__(256) void prep_all(
    const float* __restrict__ W1, const float* __restrict__ W2,
    bf16* __restrict__ W1T, bf16* __restrict__ W2T,
    const float* __restrict__ Wpre, const float* __restrict__ Wloc,
    const float* __restrict__ Wgcn, const float* __restrict__ Wpost,
    bf16* __restrict__ WpreLocT, bf16* __restrict__ Wg0T, bf16* __restrict__ Wg1T,
    bf16* __restrict__ WpostT,
    const float* __restrict__ bpre, const float* __restrict__ bloc,
    float* __restrict__ biasPL, float* __restrict__ outq) {
  __shared__ bf16 tile[64 * 68];
  int blk = blockIdx.x;
  int tid = threadIdx.x;
  if (blk < 128) {                       // tiled transpose W1/W2 (512x512 each)
    const float* W = (blk < 64) ? W1 : W2;
    bf16* WT = (blk < 64) ? W1T : W2T;
    int t = blk & 63;
    int tk0 = (t >> 3) * 64, tn0 = (t & 7) * 64;
#pragma unroll
    for (int p = 0; p < 4; p++) {
      int kr = p * 16 + (tid >> 4), nc = (tid & 15) * 4;
      float4 f = *(const float4*)(W + (size_t)(tk0 + kr) * 512 + tn0 + nc);
      bf16x4 v; v[0] = (bf16)f.x; v[1] = (bf16)f.y; v[2] = (bf16)f.z; v[3] = (bf16)f.w;
      *(bf16x4*)&tile[kr * 68 + nc] = v;
    }
    __syncthreads();
#pragma unroll
    for (int p = 0; p < 4; p++) {
      int nr = p * 16 + (tid >> 4), kc = (tid & 15) * 4;
      bf16x4 v;
#pragma unroll
      for (int i = 0; i < 4; i++) v[i] = tile[(kc + i) * 68 + nr];
      *(bf16x4*)(WT + (size_t)(tn0 + nr) * 512 + tk0 + kc) = v;
    }
    return;
  }
  blk -= 128;
  if (blk < 448) {                       // small transposes
    int id = blk * 256 + tid;
    if (id < 16384) { tp(Wpre, WpreLocT, id, 7, 128); return; } id -= 16384;
    if (id < 32768) { tp(Wloc, WpreLocT + 16384, id, 7, 256); return; } id -= 32768;
    if (id < 16384) { tp(Wgcn, Wg0T, id, 7, 128); return; } id -= 16384;
    if (id < 16384) { tp(Wgcn + 16384, Wg1T, id, 7, 128); return; } id -= 16384;
    tp(Wpost, WpostT, id, 7, 256);
    return;
  }
  blk -= 448;
  if (blk == 0) {                        // bias concat
    if (tid < 128) biasPL[tid] = bpre[tid];
    biasPL[128 + tid] = bloc[tid];
    return;
  }
  blk -= 1;
  // zero d_out: 64 blocks x 256 threads x 4 float4 = 262144 floats
  float4 z = {0.f, 0.f, 0.f, 0.f};
#pragma unroll
  for (int i = 0; i < 4; i++)
    ((float4*)outq)[(size_t)blk * 1024 + i * 256 + tid] = z;
}

// ---- K1 + collapsed GCN chain + h-precompute; BK=32 dbuf GEMM core ----
// 768 blocks XCD-swizzled (3 n-siblings/m-tile). nt0: pre-GEMM -> pool ->
// 3-layer chain -> g (LDS) -> h = g@W1a + b1. nt1,2: loc.
// A staged from fp32 obs with load/compute/commit split (vmcnt wait for A data
// lands after compute); B via global_load_lds. Swizzle: phys chunk c of row r
// holds logical c ^ ((r>>1)&3).
__global__ __launch_bounds__(256, 4) void k1c(
    const float* __restrict__ obs, const bf16* __restrict__ WpreLocT,
    const float* __restrict__ biasPL,
    const bf16* __restrict__ Wg0T, const bf16* __restrict__ Wg1T,
    const bf16* __restrict__ WpostT, const float* __restrict__ b_gcn,
    const float* __restrict__ b_post,
    const bf16* __restrict__ W1T, const float* __restrict__ b1,
    bf16* __restrict__ loc, float* __restrict__ h) {
  __shared__ bf16 smem[16384];   // 2 x (A 4096 + B 4096)

  const int tid = threadIdx.x;
  const int id = blockIdx.x;
  const int s = id >> 3;
  const int n_idx = s % 3;
  const int m0 = ((id & 7) + 8 * (s / 3)) * 128;
  const int n0 = n_idx * 128;

  f32x4 acc[4][4] = {};
  const int lane = tid & 63, wave = tid >> 6;
  const int wm = (wave >> 1) * 64, wn = (wave & 1) * 64;
  const int lm = lane & 15, quad = lane >> 4;

  float4 pa[4];                          // A prefetch regs (2 chunks x 2 float4)

  auto loadA = [&](int kt) {
#pragma unroll
    for (int it = 0; it < 2; it++) {
      int idx = it * 256 + tid;
      int row = idx >> 2;
      int c = idx & 3;
      int cv = c ^ ((row >> 1) & 3);
      const float* src = obs + (size_t)(m0 + row) * 128 + kt * 32 + cv * 8;
      pa[it * 2] = *(const float4*)src;
      pa[it * 2 + 1] = *(const float4*)(src + 4);
    }
  };
  auto stageB = [&](int kt, int buf) {
    bf16* Bd = smem + buf * 8192 + 4096;
#pragma unroll
    for (int it = 0; it < 2; it++) {
      int idx = it * 256 + tid;
      int row = idx >> 2;
      int c = idx & 3;
      int cv = c ^ ((row >> 1) & 3);
      const bf16* gb = WpreLocT + (size_t)(n0 + row) * 128 + kt * 32 + cv * 8;
      __builtin_amdgcn_global_load_lds(GL(gb), SH(&Bd[(idx & ~63) * 8]), 16, 0, 0);
    }
  };
  auto commitA = [&](int buf) {
    bf16* Ad = smem + buf * 8192;
#pragma unroll
    for (int it = 0; it < 2; it++) {
      int idx = it * 256 + tid;
      int row = idx >> 2;
      int c = idx & 3;
      float4 f0 = pa[it * 2], f1 = pa[it * 2 + 1];
      bf16x8 v;
      v[0] = (bf16)f0.x; v[1] = (bf16)f0.y; v[2] = (bf16)f0.z; v[3] = (bf16)f0.w;
      v[4] = (bf16)f1.x; v[5] = (bf16)f1.y; v[6] = (bf16)f1.z; v[7] = (bf16)f1.w;
      *(bf16x8*)&Ad[row * 32 + c * 8] = v;
    }
  };
  auto compute = [&](int buf) {
    const bf16* Ar = smem + buf * 8192;
    const bf16* Br = smem + buf * 8192 + 4096;
    bf16x8 a[4], b[4];
#pragma unroll
    for (int i = 0; i < 4; i++) {
      int r = wm + lm + i * 16;
      a[i] = *(const bf16x8*)&Ar[r * 32 + ((quad ^ ((r >> 1) & 3)) * 8)];
    }
#pragma unroll
    for (int j = 0; j < 4; j++) {
      int r = wn + lm + j * 16;
      b[j] = *(const bf16x8*)&Br[r * 32 + ((quad ^ ((r >> 1) & 3)) * 8)];
    }
#pragma unroll
    for (int i = 0; i < 4; i++)
#pragma unroll
      for (int j = 0; j < 4; j++)
        acc[i][j] = MFMA(a[i], b[j], acc[i][j]);
  };

  loadA(0); stageB(0, 0); commitA(0);
  __syncthreads();
#pragma unroll
  for (int i = 0; i < 4; ++i) {
    if (i + 1 < 4) { loadA(i + 1); stageB(i + 1, (i + 1) & 1); }
    compute(i & 1);
    if (i + 1 < 4) commitA((i + 1) & 1);
    __syncthreads();
  }

  if (n_idx == 0) {
    bf16* xs = smem;                  // 16 x 136
    bf16* x2 = smem + 2176;           // 16 x 136
    bf16* gS = smem + 4352;           // 16 x 264
#pragma unroll
    for (int i = 0; i < 4; i++) {
      int sl = (wave >> 1) * 4 + i;
#pragma unroll
      for (int j = 0; j < 4; j++) {
        int col = wn + j * 16 + lm;
        float bb = biasPL[col];
        float v = 0.f;
#pragma unroll
        for (int r = 0; r < 4; r++) v += fmaxf(acc[i][j][r] + bb, 0.f);
        v += __shfl_xor(v, 16);
        v += __shfl_xor(v, 32);
        if (quad == 0) xs[sl * 136 + col] = (bf16)(v * 0.0625f);
        else if (quad == 1) xs[(8 + sl) * 136 + col] = (bf16)0.f;
      }
    }
    __syncthreads();
    {  // l0: xs -> x2
      f32x4 c2[2] = {};
#pragma unroll
      for (int ku = 0; ku < 4; ++ku) {
        bf16x8 a = *(const bf16x8*)&xs[lm * 136 + (ku * 4 + quad) * 8];
#pragma unroll
        for (int jn = 0; jn < 2; ++jn) {
          int col = (wave * 2 + jn) * 16 + lm;
          bf16x8 b = *(const bf16x8*)&Wg0T[(size_t)col * 128 + ku * 32 + quad * 8];
          c2[jn] = MFMA(a, b, c2[jn]);
        }
      }
      __syncthreads();
#pragma unroll
      for (int jn = 0; jn < 2; ++jn) {
        int col = (wave * 2 + jn) * 16 + lm;
        float bb = b_gcn[col];
#pragma unroll
        for (int r = 0; r < 4; ++r)
          x2[(quad * 4 + r) * 136 + col] = (bf16)fmaxf(c2[jn][r] + bb, 0.f);
      }
    }
    __syncthreads();
    {  // l1: x2 -> xs
      f32x4 c2[2] = {};
#pragma unroll
      for (int ku = 0; ku < 4; ++ku) {
        bf16x8 a = *(const bf16x8*)&x2[lm * 136 + (ku * 4 + quad) * 8];
#pragma unroll
        for (int jn = 0; jn < 2; ++jn) {
          int col = (wave * 2 + jn) * 16 + lm;
          bf16x8 b = *(const bf16x8*)&Wg1T[(size_t)col * 128 + ku * 32 + quad * 8];
          c2[jn] = MFMA(a, b, c2[jn]);
        }
      }
      __syncthreads();
#pragma unroll
      for (int jn = 0; jn < 2; ++jn) {
        int col = (wave * 2 + jn) * 16 + lm;
        float bb = b_gcn[128 + col];
#pragma unroll
        for (int r = 0; r < 4; ++r)
          xs[(quad * 4 + r) * 136 + col] = (bf16)fmaxf(c2[jn][r] + bb, 0.f);
      }
    }
    __syncthreads();
    {  // l2: xs -> gS
      f32x4 c3[4] = {};
#pragma unroll
      for (int ku = 0; ku < 4; ++ku) {
        bf16x8 a = *(const bf16x8*)&xs[lm * 136 + (ku * 4 + quad) * 8];
#pragma unroll
        for (int jn = 0; jn < 4; ++jn) {
          int col = (wave * 4 + jn) * 16 + lm;
          bf16x8 b = *(const bf16x8*)&WpostT[(size_t)col * 128 + ku * 32 + quad * 8];
          c3[jn] = MFMA(a, b, c3[jn]);
        }
      }
#pragma unroll
      for (int jn = 0; jn < 4; ++jn) {
        int col = (wave * 4 + jn) * 16 + lm;
        float bb = b_post[col];
#pragma unroll
        for (int r = 0; r < 4; ++r)
          gS[(quad * 4 + r) * 264 + col] = (bf16)fmaxf(c3[jn][r] + bb, 0.f);
      }
    }
    __syncthreads();
    {  // h = g @ W1a + b1
      f32x4 hacc[8] = {};
#pragma unroll
      for (int ku = 0; ku < 8; ++ku) {
        bf16x8 a = *(const bf16x8*)&gS[lm * 264 + ku * 32 + quad * 8];
#pragma unroll
        for (int jn = 0; jn < 8; ++jn) {
          int col = (wave * 8 + jn) * 16 + lm;
          bf16x8 b = *(const bf16x8*)&W1T[(size_t)col * 512 + ku * 32 + quad * 8];
          hacc[jn] = MFMA(a, b, hacc[jn]);
        }
      }
      int sample0 = m0 >> 4;
#pragma unroll
      for (int jn = 0; jn < 8; ++jn) {
        int col = (wave * 8 + jn) * 16 + lm;
        float bb = b1[col];
#pragma unroll
        for (int r = 0; r < 4; ++r) {
          int row = quad * 4 + r;
          if (row < 8)
            h[(size_t)(sample0 + row) * 512 + col] = hacc[jn][r] + bb;
        }
      }
    }
  } else {
#pragma unroll
    for (int i = 0; i < 4; i++)
#pragma unroll
      for (int j = 0; j < 4; j++) {
        int col = wn + j * 16 + lm;
        float bb = biasPL[n0 + col];
#pragma unroll
        for (int r = 0; r < 4; r++) {
          int row = wm + i * 16 + quad * 4 + r;
          smem[row * 128 + col] = (bf16)fmaxf(acc[i][j][r] + bb, 0.f);
        }
      }
    __syncthreads();
    const int coff = n0 - 128;
#pragma unroll
    for (int c = 0; c < 8; c++) {
      int ci = c * 256 + tid;
      int row = ci >> 4, col8 = (ci & 15) * 8;
      *(bf16x8*)&loc[(size_t)(m0 + row) * 256 + coff + col8] = *(const bf16x8*)&smem[row * 128 + col8];
    }
  }
}

// ---- K3/K4: 128x128 GEMM, BK=32, explicit LDS double-buffer (R14 winner) ----
template <bool HREP>
__global__ __launch_bounds__(256, 4) void gemm_k(
    const bf16* __restrict__ Ab, const bf16* __restrict__ BT,
    const float* __restrict__ bias, const float* __restrict__ hrep,
    bf16* __restrict__ C,
    const float* __restrict__ W3, const float* __restrict__ b3,
    float* __restrict__ outq) {
  __shared__ bf16 smem[16384];   // 2 x (A 4096 + B 4096)

  const int tid = threadIdx.x;
  const int id = blockIdx.x;
  const int s = id >> 3;
  const int n_idx = s & 3;
  const int m0 = ((id & 7) + 8 * (s >> 2)) * 128;
  const int n0 = n_idx * 128;

  f32x4 acc[4][4] = {};
  const int lane = tid & 63, wave = tid >> 6;
  const int wm = (wave >> 1) * 64, wn = (wave & 1) * 64;
  const int lm = lane & 15, quad = lane >> 4;

  auto stage = [&](int kt, int buf) {
    bf16* Ad = smem + buf * 8192;
    bf16* Bd = smem + buf * 8192 + 4096;
    int k0 = kt * 32;
#pragma unroll
    for (int it = 0; it < 2; it++) {
      int idx = it * 256 + tid;
      int row = idx >> 2;
      int c = idx & 3;
      int cv = c ^ ((row >> 1) & 3);
      int kk = k0 + cv * 8;
      const bf16* ga = HREP ? (Ab + (size_t)(m0 + row) * 256 + kk)
                            : (Ab + (size_t)(m0 + row) * 512 + kk);
      __builtin_amdgcn_global_load_lds(GL(ga), SH(&Ad[(idx & ~63) * 8]), 16, 0, 0);
      const bf16* gb = HREP ? (BT + (size_t)(n0 + row) * 512 + 256 + kk)
                            : (BT + (size_t)(n0 + row) * 512 + kk);
      __builtin_amdgcn_global_load_lds(GL(gb), SH(&Bd[(idx & ~63) * 8]), 16, 0, 0);
    }
  };

  auto compute = [&](int buf) {
    const bf16* Ar = smem + buf * 8192;
    const bf16* Br = smem + buf * 8192 + 4096;
    bf16x8 a[4], b[4];
#pragma unroll
    for (int i = 0; i < 4; i++) {
      int r = wm + lm + i * 16;
      a[i] = *(const bf16x8*)&Ar[r * 32 + ((quad ^ ((r >> 1) & 3)) * 8)];
    }
#pragma unroll
    for (int j = 0; j < 4; j++) {
      int r = wn + lm + j * 16;
      b[j] = *(const bf16x8*)&Br[r * 32 + ((quad ^ ((r >> 1) & 3)) * 8)];
    }
#pragma unroll
    for (int i = 0; i < 4; i++)
#pragma unroll
      for (int j = 0; j < 4; j++)
        acc[i][j] = MFMA(a[i], b[j], acc[i][j]);
  };

  const int NIT = HREP ? 8 : 16;
  stage(0, 0);
  __syncthreads();
#pragma unroll 2
  for (int i = 0; i < NIT; ++i) {
    if (i + 1 < NIT) stage(i + 1, (i + 1) & 1);
    compute(i & 1);
    __syncthreads();
  }

  if (HREP) {
#pragma unroll
    for (int i = 0; i < 4; i++) {
      int sample = (m0 + wm + i * 16) >> 4;
#pragma unroll
      for (int j = 0; j < 4; j++) {
        int col = n0 + wn + j * 16 + lm;
        float hv = hrep[(size_t)sample * 512 + col];
#pragma unroll
        for (int r = 0; r < 4; r++) {
          int row = wm + i * 16 + quad * 4 + r;
          smem[row * 128 + (col - n0)] = (bf16)fmaxf(acc[i][j][r] + hv, 0.f);
        }
      }
    }
    __syncthreads();
#pragma unroll
    for (int c = 0; c < 8; c++) {
      int ci = c * 256 + tid;
      int row = ci >> 4, col8 = (ci & 15) * 8;
      *(bf16x8*)&C[(size_t)(m0 + row) * 512 + n0 + col8] = *(const bf16x8*)&smem[row * 128 + col8];
    }
  } else {
#pragma unroll
    for (int i = 0; i < 4; i++)
#pragma unroll
      for (int j = 0; j < 4; j++) {
        int col = wn + j * 16 + lm;
        float bb = bias[n0 + col];
#pragma unroll
        for (int r = 0; r < 4; r++) {
          int row = wm + i * 16 + quad * 4 + r;
          smem[row * 128 + col] = (bf16)fmaxf(acc[i][j][r] + bb, 0.f);
        }
      }
    __syncthreads();
    int n = lane & 7;
    int kg = lane >> 3;
    float w3r[16];
#pragma unroll
    for (int i = 0; i < 16; i++) w3r[i] = W3[(size_t)(n0 + kg * 16 + i) * 8 + n];
    float bn = (n_idx == 0) ? b3[n] : 0.f;
    int rbase = wave * 32;
    for (int rr = 0; rr < 32; rr++) {
      const bf16* zr = &smem[(rbase + rr) * 128 + kg * 16];
      bf16x8 z0 = *(const bf16x8*)zr;
      bf16x8 z1v = *(const bf16x8*)(zr + 8);
      float v = 0.f;
#pragma unroll
      for (int i = 0; i < 8; i++) v += (float)z0[i] * w3r[i];
#pragma unroll
      for (int i = 0; i < 8; i++) v += (float)z1v[i] * w3r[8 + i];
      v += __shfl_down(v, 32);
      v += __shfl_down(v, 16);
      v += __shfl_down(v, 8);
      if (lane < 8) atomicAdd(&outq[(size_t)(m0 + rbase + rr) * 8 + n], v + bn);
    }
  }
}

extern "C" void kernel_launch(void* const* d_in, const int* in_sizes, int n_in,
                              void* d_out, int out_size, void* d_ws, size_t ws_size,
                              hipStream_t stream) {
  const float* obs    = (const float*)d_in[0];
  const float* W_pre  = (const float*)d_in[1];
  const float* b_pre  = (const float*)d_in[2];
  const float* W_gcn  = (const float*)d_in[3];
  const float* b_gcn  = (const float*)d_in[4];
  const float* W_post = (const float*)d_in[5];
  const float* b_post = (const float*)d_in[6];
  const float* W_loc  = (const float*)d_in[7];
  const float* b_loc  = (const float*)d_in[8];
  const float* W1     = (const float*)d_in[9];
  const float* b1     = (const float*)d_in[10];
  const float* W2     = (const float*)d_in[11];
  const float* b2     = (const float*)d_in[12];
  const float* W3     = (const float*)d_in[13];
  const float* b3     = (const float*)d_in[14];
  float* out = (float*)d_out;

  char* p = (char*)d_ws;
  auto alloc = [&](size_t bytes) { char* r = p; p += (bytes + 255) & ~(size_t)255; return r; };
  bf16* WpreLocT = (bf16*)alloc(384 * 128 * 2);
  float* biasPL  = (float*)alloc(384 * 4);
  bf16* Wg0T   = (bf16*)alloc(128 * 128 * 2);
  bf16* Wg1T   = (bf16*)alloc(128 * 128 * 2);
  bf16* WpostT = (bf16*)alloc(256 * 128 * 2);
  bf16* W1T    = (bf16*)alloc(512 * 512 * 2);
  bf16* W2T    = (bf16*)alloc(512 * 512 * 2);
  bf16* locB   = (bf16*)alloc((size_t)32768 * 256 * 2);
  float* hB    = (float*)alloc((size_t)2048 * 512 * 4);
  bf16* z1B    = (bf16*)alloc((size_t)32768 * 512 * 2);

  // P: weight prep + bias + d_out zero
  prep_all<<<641, 256, 0, stream>>>(W1, W2, W1T, W2T,
                                    W_pre, W_loc, W_gcn, W_post,
                                    WpreLocT, Wg0T, Wg1T, WpostT,
                                    b_pre, b_loc, biasPL, out);
  // K1+chain+h (dbuf BK=32)
  k1c<<<768, 256, 0, stream>>>(obs, WpreLocT, biasPL,
                               Wg0T, Wg1T, WpostT, b_gcn, b_post,
                               W1T, b1, locB, hB);
  // K3: z1 = relu(loc @ W1b + h_rep), K=256, double-buffered
  gemm_k<true><<<1024, 256, 0, stream>>>(locB, W1T, nullptr, hB, z1B,
                                         nullptr, nullptr, nullptr);
  // K4: z2 = relu(z1 @ W2 + b2) + q-head, K=512, double-buffered
  gemm_k<false><<<1024, 256, 0, stream>>>(z1B, W2T, b2, nullptr, nullptr,
                                          W3, b3, out);
}